// Round 9
// baseline (539.888 us; speedup 1.0000x reference)
//
#include <hip/hip_runtime.h>
#include <stdint.h>

#define NM 128    // matrix dim / electrons
#define NT 1024   // 16 waves; wave w owns cols [8w..8w+7]; lane l owns rows l, l+64
                  // lane state: sv[j] = (S[l][8w+j], S[l+64][8w+j])

typedef float v2f __attribute__((ext_vector_type(2)));

__device__ __forceinline__ float readlane_f(float v, int lane) {
    return __int_as_float(__builtin_amdgcn_readlane(__float_as_int(v), lane));
}

// Full 64-lane unsigned max via DPP (VALU pipe); result valid in lane 63.
__device__ __forceinline__ unsigned wave_max_dpp(unsigned x) {
    int v = (int)x;
#define DPP_STEP(ctrl) \
    { int o = __builtin_amdgcn_update_dpp(0, v, ctrl, 0xf, 0xf, true); \
      v = ((unsigned)o > (unsigned)v) ? o : v; }
    DPP_STEP(0x111)  // row_shr:1
    DPP_STEP(0x112)  // row_shr:2
    DPP_STEP(0x114)  // row_shr:4
    DPP_STEP(0x118)  // row_shr:8
    DPP_STEP(0x142)  // row_bcast:15
    DPP_STEP(0x143)  // row_bcast:31
#undef DPP_STEP
    return (unsigned)v;
}

__device__ __forceinline__ unsigned pack_key(float v, int r) {
    // monotone in |v|; drop 6 mantissa LSBs to make room for the 7-bit row id
    return (((__float_as_uint(v) & 0x7fffffffu) >> 6) << 7) | (unsigned)r;
}

// max(ka,kb) over the wave, broadcast to all lanes (uniform result)
__device__ __forceinline__ unsigned argmax_bcast(unsigned ka, unsigned kb) {
    const unsigned m = wave_max_dpp(ka > kb ? ka : kb);
    return (unsigned)__builtin_amdgcn_readlane((int)m, 63);
}

// Interleaved rank-2 update of an 8-col slab. Step k applied BEFORE reading
// u1: row p1's registers already hold post-step-k values, so no fixup FMA.
// lm0/lm1 are pre-multiplied AND pre-zeroed (publisher applied elim masking).
template<bool P0LO, bool P1LO>
__device__ __forceinline__ void update8(v2f (&sv)[8], int p0l, int p1l,
                                        v2f lm0, v2f lm1) {
#pragma unroll
    for (int j = 0; j < 8; ++j) {
        const float u0 = P0LO ? readlane_f(sv[j].x, p0l) : readlane_f(sv[j].y, p0l);
        sv[j] = __builtin_elementwise_fma((v2f){-u0, -u0}, lm0, sv[j]);
        const float u1 = P1LO ? readlane_f(sv[j].x, p1l) : readlane_f(sv[j].y, p1l);
        sv[j] = __builtin_elementwise_fma((v2f){-u1, -u1}, lm1, sv[j]);
    }
}

__global__ __launch_bounds__(NT, 8)
void slater_logdet(const float* __restrict__ rs,
                   const float* __restrict__ kpts,
                   const float* __restrict__ csw,
                   const float* __restrict__ ssw,
                   float* __restrict__ out) {
    // Per-round write-once buffers (async dataflow; no per-round barriers).
    // colv[rd][r] = {l0, l1}: PRE-MULTIPLIED, PRE-ZEROED multipliers for round rd.
    __shared__ float2   colv[NM / 2][NM];   // 64.5 KB
    __shared__ uint2    keys[NM / 2];       // pivot-id keys per round
    __shared__ float2   pivs[NM / 2];       // exact pivots (epilogue log)
    __shared__ unsigned flags[NM / 2];      // publish flags (0 = not ready)
    __shared__ float    redf[2];

    const int t  = threadIdx.x;
    const int b  = blockIdx.x;
    const int w  = t >> 6;    // wave id = 8-col slab id
    const int l  = t & 63;
    const int c0 = w << 3;
    const int r0 = l, r1 = l + 64;

    if (t < NM / 2) flags[t] = 0;   // LDS is uninitialized garbage

    v2f sv[8];   // sv[j] = (row r0, row r1) at col c0+j
    {
        const float x0 = rs[(b * NM + r0) * 3 + 0];
        const float y0 = rs[(b * NM + r0) * 3 + 1];
        const float z0 = rs[(b * NM + r0) * 3 + 2];
        const float x1 = rs[(b * NM + r1) * 3 + 0];
        const float y1 = rs[(b * NM + r1) * 3 + 1];
        const float z1 = rs[(b * NM + r1) * 3 + 2];
#pragma unroll
        for (int j = 0; j < 8; ++j) {
            const int m = c0 + j;  // wave-uniform -> scalar loads
            const float kx = kpts[m * 3 + 0], ky = kpts[m * 3 + 1], kz = kpts[m * 3 + 2];
            const float cw = csw[m], sw = ssw[m];
            float sn, cn;
            __sincosf(kx * x0 + ky * y0 + kz * z0, &sn, &cn);
            sv[j].x = cw * cn - sw * sn;
            __sincosf(kx * x1 + ky * y1 + kz * z1, &sn, &cn);
            sv[j].y = cw * cn - sw * sn;
        }
    }
    __syncthreads();   // flags zeroed & visible before any publish/poll

    bool elim0 = false, elim1 = false;
    volatile unsigned* vflags = (volatile unsigned*)flags;

    // ---- bootstrap: wave 0 publishes round 0 (steps 0,1) ----
    if (w == 0) {
        const float c0a = sv[0].x, c0b = sv[0].y;
        const float c1p = sv[1].x, c1q = sv[1].y;
        const unsigned key0 = argmax_bcast(pack_key(c0a, r0), pack_key(c0b, r1));
        const int p0 = (int)(key0 & 127u);
        const float piv0 = (p0 < 64) ? readlane_f(c0a, p0) : readlane_f(c0b, p0 - 64);
        const float u01  = (p0 < 64) ? readlane_f(c1p, p0) : readlane_f(c1q, p0 - 64);
        const float rcp0 = __builtin_amdgcn_rcpf(piv0);
        const bool e0 = (r0 == p0), e1 = (r1 == p0);
        const float l0a = e0 ? 0.0f : c0a * rcp0;
        const float l0b = e1 ? 0.0f : c0b * rcp0;
        const float c1a = c1p - l0a * u01;
        const float c1b = c1q - l0b * u01;
        const unsigned key1 = argmax_bcast(e0 ? 0u : pack_key(c1a, r0),
                                           e1 ? 0u : pack_key(c1b, r1));
        const int p1 = (int)(key1 & 127u);
        const float piv1 = (p1 < 64) ? readlane_f(c1a, p1) : readlane_f(c1b, p1 - 64);
        const float rcp1 = __builtin_amdgcn_rcpf(piv1);
        const bool f0 = e0 || (r0 == p1), f1 = e1 || (r1 == p1);
        colv[0][r0] = make_float2(l0a, f0 ? 0.0f : c1a * rcp1);
        colv[0][r1] = make_float2(l0b, f1 ? 0.0f : c1b * rcp1);
        if (l == 0) { keys[0] = make_uint2(key0, key1);
                      pivs[0] = make_float2(piv0, piv1); }
        __threadfence_block();              // data lands before flag
        if (l == 0) vflags[0] = 1u;
    }

    // ---- async main loop: each wave runs its live rounds at its own pace ----
    const int lastLive = 4 * w + 2;
    const int liveEnd  = lastLive < 62 ? lastLive : 62;
    for (int rd = 0; rd <= liveEnd; ++rd) {
        // wait for round rd's publish (wave-uniform spin, broadcast LDS read)
        if (vflags[rd] == 0u) {
            do { __builtin_amdgcn_s_sleep(1); } while (vflags[rd] == 0u);
        }
        __threadfence_block();   // acquire: no reads hoisted above the flag

        const uint2 kk = keys[rd];
        const int p0u = __builtin_amdgcn_readfirstlane((int)(kk.x & 127u));
        const int p1u = __builtin_amdgcn_readfirstlane((int)(kk.y & 127u));
        elim0 |= (r0 == p0u) | (r0 == p1u);
        elim1 |= (r1 == p0u) | (r1 == p1u);

        const float2 la = colv[rd][r0];   // pre-zeroed premultipliers
        const float2 lb = colv[rd][r1];
        const v2f lm0 = { la.x, lb.x };
        const v2f lm1 = { la.y, lb.y };

        if (p0u < 64) {
            if (p1u < 64) update8<true, true >(sv, p0u,      p1u,      lm0, lm1);
            else          update8<true, false>(sv, p0u,      p1u - 64, lm0, lm1);
        } else {
            if (p1u < 64) update8<false, true >(sv, p0u - 64, p1u,      lm0, lm1);
            else          update8<false, false>(sv, p0u - 64, p1u - 64, lm0, lm1);
        }

        // ---- look-ahead publish of round rd+1 (this wave is owner?) ----
        const int k2 = 2 * rd + 2;
        if (w == (k2 >> 3)) {
            const int jb = (k2 & 7) >> 1;        // uniform in [0,4)
            const v2f e0v = (jb & 1) ? sv[2] : sv[0];
            const v2f e1v = (jb & 1) ? sv[6] : sv[4];
            const v2f c2  = (jb & 2) ? e1v : e0v;
            const v2f o0v = (jb & 1) ? sv[3] : sv[1];
            const v2f o1v = (jb & 1) ? sv[7] : sv[5];
            const v2f c3  = (jb & 2) ? o1v : o0v;
            const unsigned key2 = argmax_bcast(elim0 ? 0u : pack_key(c2.x, r0),
                                               elim1 ? 0u : pack_key(c2.y, r1));
            const int p2 = (int)(key2 & 127u);
            const float piv2 = (p2 < 64) ? readlane_f(c2.x, p2) : readlane_f(c2.y, p2 - 64);
            const float u23  = (p2 < 64) ? readlane_f(c3.x, p2) : readlane_f(c3.y, p2 - 64);
            const float rcp2 = __builtin_amdgcn_rcpf(piv2);
            const bool f0 = elim0 || (r0 == p2), f1 = elim1 || (r1 == p2);
            const float l2a = f0 ? 0.0f : c2.x * rcp2;
            const float l2b = f1 ? 0.0f : c2.y * rcp2;
            const float c3a = c3.x - l2a * u23;
            const float c3b = c3.y - l2b * u23;
            const unsigned key3 = argmax_bcast(f0 ? 0u : pack_key(c3a, r0),
                                               f1 ? 0u : pack_key(c3b, r1));
            const int p3 = (int)(key3 & 127u);
            const float piv3 = (p3 < 64) ? readlane_f(c3a, p3) : readlane_f(c3b, p3 - 64);
            const float rcp3 = __builtin_amdgcn_rcpf(piv3);
            const bool g0 = f0 || (r0 == p3), g1 = f1 || (r1 == p3);
            colv[rd + 1][r0] = make_float2(l2a, g0 ? 0.0f : c3a * rcp3);
            colv[rd + 1][r1] = make_float2(l2b, g1 ? 0.0f : c3b * rcp3);
            if (l == 0) { keys[rd + 1] = make_uint2(key2, key3);
                          pivs[rd + 1] = make_float2(piv2, piv3); }
            __threadfence_block();          // data lands before flag
            if (l == 0) vflags[rd + 1] = 1u;
        }
    }
    __syncthreads();   // all 64 pivot pairs published & visible

    // ---- log|det| = sum log|piv_k| over the write-once pivs array ----
    float lg = 0.0f;
    if (t < NM) {
        const float2 pv2 = pivs[t >> 1];
        lg = __logf(fabsf((t & 1) ? pv2.y : pv2.x));
#pragma unroll
        for (int off = 32; off > 0; off >>= 1)
            lg += __shfl_xor(lg, off, 64);
        if ((t & 63) == 0) redf[t >> 6] = lg;
    }
    __syncthreads();
    if (t == 0) out[b] = redf[0] + redf[1];
}

extern "C" void kernel_launch(void* const* d_in, const int* in_sizes, int n_in,
                              void* d_out, int out_size, void* d_ws, size_t ws_size,
                              hipStream_t stream) {
    const float* rs = (const float*)d_in[0];
    const float* kp = (const float*)d_in[1];
    const float* cs = (const float*)d_in[2];
    const float* ss = (const float*)d_in[3];
    float* out = (float*)d_out;
    const int batch = in_sizes[0] / (NM * 3);  // 4096
    slater_logdet<<<dim3(batch), dim3(NT), 0, stream>>>(rs, kp, cs, ss, out);
}

// Round 10
// 455.249 us; speedup vs baseline: 1.1859x; 1.1859x over previous
//
#include <hip/hip_runtime.h>
#include <stdint.h>

#define NM 128    // matrix dim / electrons
#define NT 1024   // 16 waves; wave w owns cols [8w..8w+7]; lane l owns rows l, l+64
                  // lane state: sv[j] = (S[l][8w+j], S[l+64][8w+j])

typedef float v2f __attribute__((ext_vector_type(2)));

__device__ __forceinline__ float readlane_f(float v, int lane) {
    return __int_as_float(__builtin_amdgcn_readlane(__float_as_int(v), lane));
}

// Full 64-lane unsigned max via DPP (VALU pipe); result valid in lane 63.
__device__ __forceinline__ unsigned wave_max_dpp(unsigned x) {
    int v = (int)x;
#define DPP_STEP(ctrl) \
    { int o = __builtin_amdgcn_update_dpp(0, v, ctrl, 0xf, 0xf, true); \
      v = ((unsigned)o > (unsigned)v) ? o : v; }
    DPP_STEP(0x111)  // row_shr:1
    DPP_STEP(0x112)  // row_shr:2
    DPP_STEP(0x114)  // row_shr:4
    DPP_STEP(0x118)  // row_shr:8
    DPP_STEP(0x142)  // row_bcast:15
    DPP_STEP(0x143)  // row_bcast:31
#undef DPP_STEP
    return (unsigned)v;
}

__device__ __forceinline__ unsigned pack_key(float v, int r) {
    // monotone in |v|; drop 6 mantissa LSBs to make room for the 7-bit row id
    return (((__float_as_uint(v) & 0x7fffffffu) >> 6) << 7) | (unsigned)r;
}

// max(ka,kb) over the wave, broadcast to all lanes (uniform result)
__device__ __forceinline__ unsigned argmax_bcast(unsigned ka, unsigned kb) {
    const unsigned m = wave_max_dpp(ka > kb ? ka : kb);
    return (unsigned)__builtin_amdgcn_readlane((int)m, 63);
}

// read pivot row p's element of a (row r0, row r1) register pair; p uniform
__device__ __forceinline__ float sel_readlane(v2f c, int p) {
    return (p < 64) ? readlane_f(c.x, p) : readlane_f(c.y, p - 64);
}

// one elimination step on the 8-col slab: extract pivot row (uniform branch,
// 8 readlanes) then 8 pk_fma. lm is the pre-multiplied, pre-zeroed pair.
__device__ __forceinline__ void extract_apply(v2f (&sv)[8], int p, v2f lm) {
    float u[8];
    if (p < 64) {
#pragma unroll
        for (int j = 0; j < 8; ++j) u[j] = readlane_f(sv[j].x, p);
    } else {
#pragma unroll
        for (int j = 0; j < 8; ++j) u[j] = readlane_f(sv[j].y, p - 64);
    }
#pragma unroll
    for (int j = 0; j < 8; ++j)
        sv[j] = __builtin_elementwise_fma((v2f){-u[j], -u[j]}, lm, sv[j]);
}

// look-ahead: locally factor 4 cols sv[B..B+3] IN PLACE (they die next round),
// publishing pre-multiplied+pre-zeroed multipliers, keys, exact pivots.
template<int B>
__device__ __forceinline__ void lookahead4(v2f (&sv)[8], bool e0, bool e1,
                                           int r0, int r1, int l,
                                           float2 (*colvN)[64],
                                           uint4* keySlot, float4* pivSlot) {
    unsigned kk[4]; float pv[4];
#pragma unroll
    for (int i = 0; i < 4; ++i) {
        const v2f c = sv[B + i];
        const unsigned key = argmax_bcast(e0 ? 0u : pack_key(c.x, r0),
                                          e1 ? 0u : pack_key(c.y, r1));
        const int pu = __builtin_amdgcn_readfirstlane((int)(key & 127u));
        const float piv = sel_readlane(c, pu);
        const float rcp = __builtin_amdgcn_rcpf(piv);
        e0 = e0 || (r0 == pu);
        e1 = e1 || (r1 == pu);
        const v2f lm = { e0 ? 0.0f : c.x * rcp, e1 ? 0.0f : c.y * rcp };
        colvN[i][l] = make_float2(lm.x, lm.y);
#pragma unroll
        for (int m = i + 1; m < 4; ++m) {
            const float u = sel_readlane(sv[B + m], pu);
            sv[B + m] = __builtin_elementwise_fma((v2f){-u, -u}, lm, sv[B + m]);
        }
        kk[i] = key; pv[i] = piv;
    }
    if (l == 0) {
        *keySlot = make_uint4(kk[0], kk[1], kk[2], kk[3]);
        *pivSlot = make_float4(pv[0], pv[1], pv[2], pv[3]);
    }
}

__global__ __launch_bounds__(NT, 8)
void slater_logdet(const float* __restrict__ rs,
                   const float* __restrict__ kpts,
                   const float* __restrict__ csw,
                   const float* __restrict__ ssw,
                   float* __restrict__ out) {
    // colv[parity][step][lane]: multiplier pair {row l, row l+64} — owner lane
    // computed exactly the consumer lane's rows, so no repacking needed.
    __shared__ float2 colv[2][4][64];
    __shared__ uint4  keys[NM / 4];   // write-once pivot-id keys per round
    __shared__ float4 pivs[NM / 4];   // write-once exact pivots (epilogue log)
    __shared__ float  redf[2];

    const int t  = threadIdx.x;
    const int b  = blockIdx.x;
    const int w  = t >> 6;    // wave id = 8-col slab id
    const int l  = t & 63;
    const int c0 = w << 3;
    const int r0 = l, r1 = l + 64;

    v2f sv[8];   // sv[j] = (row r0, row r1) at col c0+j
    {
        const float x0 = rs[(b * NM + r0) * 3 + 0];
        const float y0 = rs[(b * NM + r0) * 3 + 1];
        const float z0 = rs[(b * NM + r0) * 3 + 2];
        const float x1 = rs[(b * NM + r1) * 3 + 0];
        const float y1 = rs[(b * NM + r1) * 3 + 1];
        const float z1 = rs[(b * NM + r1) * 3 + 2];
#pragma unroll
        for (int j = 0; j < 8; ++j) {
            const int m = c0 + j;  // wave-uniform -> scalar loads
            const float kx = kpts[m * 3 + 0], ky = kpts[m * 3 + 1], kz = kpts[m * 3 + 2];
            const float cw = csw[m], sw = ssw[m];
            float sn, cn;
            __sincosf(kx * x0 + ky * y0 + kz * z0, &sn, &cn);
            sv[j].x = cw * cn - sw * sn;
            __sincosf(kx * x1 + ky * y1 + kz * z1, &sn, &cn);
            sv[j].y = cw * cn - sw * sn;
        }
    }

    bool elim0 = false, elim1 = false;

    // ---- bootstrap: wave 0 factors cols 0-3 from COPIES, publishes round 0 ----
    if (w == 0) {
        v2f c[4] = { sv[0], sv[1], sv[2], sv[3] };
        bool e0 = false, e1 = false;
        unsigned kk[4]; float pv[4];
#pragma unroll
        for (int i = 0; i < 4; ++i) {
            const unsigned key = argmax_bcast(e0 ? 0u : pack_key(c[i].x, r0),
                                             e1 ? 0u : pack_key(c[i].y, r1));
            const int pu = __builtin_amdgcn_readfirstlane((int)(key & 127u));
            const float piv = sel_readlane(c[i], pu);
            const float rcp = __builtin_amdgcn_rcpf(piv);
            e0 = e0 || (r0 == pu);
            e1 = e1 || (r1 == pu);
            const v2f lm = { e0 ? 0.0f : c[i].x * rcp, e1 ? 0.0f : c[i].y * rcp };
            colv[0][i][l] = make_float2(lm.x, lm.y);
#pragma unroll
            for (int m = i + 1; m < 4; ++m) {
                const float u = sel_readlane(c[m], pu);
                c[m] = __builtin_elementwise_fma((v2f){-u, -u}, lm, c[m]);
            }
            kk[i] = key; pv[i] = piv;
        }
        if (l == 0) {
            keys[0] = make_uint4(kk[0], kk[1], kk[2], kk[3]);
            pivs[0] = make_float4(pv[0], pv[1], pv[2], pv[3]);
        }
    }
    __syncthreads();

    // ---- main loop: 31 rounds, one barrier per 4 elimination steps ----
    // Wave w's last useful round: its cols die by round 2w+1. Round 31 is
    // unnecessary (its steps only touch its own pivot cols — done in lookahead).
    const int liveEnd = (2 * w + 1 < 30) ? 2 * w + 1 : 30;
    int rd = 0;
    for (; rd <= liveEnd; ++rd) {
        const uint4 kk = keys[rd];
        const int p0 = __builtin_amdgcn_readfirstlane((int)(kk.x & 127u));
        const int p1 = __builtin_amdgcn_readfirstlane((int)(kk.y & 127u));
        const int p2 = __builtin_amdgcn_readfirstlane((int)(kk.z & 127u));
        const int p3 = __builtin_amdgcn_readfirstlane((int)(kk.w & 127u));
        elim0 |= (r0 == p0) | (r0 == p1) | (r0 == p2) | (r0 == p3);
        elim1 |= (r1 == p0) | (r1 == p1) | (r1 == p2) | (r1 == p3);

        const int par = rd & 1;
        const float2 la0 = colv[par][0][l];
        const float2 la1 = colv[par][1][l];
        const float2 la2 = colv[par][2][l];
        const float2 la3 = colv[par][3][l];

        extract_apply(sv, p0, (v2f){la0.x, la0.y});
        extract_apply(sv, p1, (v2f){la1.x, la1.y});
        extract_apply(sv, p2, (v2f){la2.x, la2.y});
        extract_apply(sv, p3, (v2f){la3.x, la3.y});

        // ---- look-ahead publish of round rd+1 (one owner wave) ----
        const int rr = rd + 1;
        if (rr < NM / 4 && w == (rr >> 1)) {
            if ((rr & 1) == 0)
                lookahead4<0>(sv, elim0, elim1, r0, r1, l,
                              colv[rr & 1], &keys[rr], &pivs[rr]);
            else
                lookahead4<4>(sv, elim0, elim1, r0, r1, l,
                              colv[rr & 1], &keys[rr], &pivs[rr]);
        }
        __syncthreads();
    }
    for (; rd < 31; ++rd) __syncthreads();   // dead waves: barrier-only

    // ---- log|det| = sum log|piv_k| over the write-once pivs array ----
    float lg = 0.0f;
    if (t < NM) {
        const float4 pb = pivs[t >> 2];
        const int cc = t & 3;
        const float pv = (cc == 0) ? pb.x : (cc == 1) ? pb.y : (cc == 2) ? pb.z : pb.w;
        lg = __logf(fabsf(pv));
#pragma unroll
        for (int off = 32; off > 0; off >>= 1)
            lg += __shfl_xor(lg, off, 64);
        if ((t & 63) == 0) redf[t >> 6] = lg;
    }
    __syncthreads();
    if (t == 0) out[b] = redf[0] + redf[1];
}

extern "C" void kernel_launch(void* const* d_in, const int* in_sizes, int n_in,
                              void* d_out, int out_size, void* d_ws, size_t ws_size,
                              hipStream_t stream) {
    const float* rs = (const float*)d_in[0];
    const float* kp = (const float*)d_in[1];
    const float* cs = (const float*)d_in[2];
    const float* ss = (const float*)d_in[3];
    float* out = (float*)d_out;
    const int batch = in_sizes[0] / (NM * 3);  // 4096
    slater_logdet<<<dim3(batch), dim3(NT), 0, stream>>>(rs, kp, cs, ss, out);
}